// Round 1
// baseline (281.537 us; speedup 1.0000x reference)
//
#include <hip/hip_runtime.h>

typedef _Float16 f16x8 __attribute__((ext_vector_type(8)));
typedef _Float16 f16x4 __attribute__((ext_vector_type(4)));
typedef float    f32x4 __attribute__((ext_vector_type(4)));

constexpr int Bc = 4, Hc = 16, Sc = 2048, Dc = 64;
constexpr int QBLK = 64, KVBLK = 64;
constexpr int NQ  = Sc / QBLK;    // 32
constexpr int NKV = Sc / KVBLK;   // 32
constexpr int LDSW = KVBLK + 8;   // 72 halves = 144 B row stride (36 banks -> uniform)

__device__ __forceinline__ float fast_exp2(float x) {
#if __has_builtin(__builtin_amdgcn_exp2f)
  return __builtin_amdgcn_exp2f(x);
#else
  return exp2f(x);
#endif
}

__global__ __launch_bounds__(256)
void attn_fwd(const float* __restrict__ Q, const float* __restrict__ K,
              const float* __restrict__ V, const int* __restrict__ M,
              float* __restrict__ O)
{
  const int bid   = blockIdx.x;
  const int qtile = bid & (NQ - 1);
  const int bh    = bid >> 5;       // b*H + h
  const int b     = bh >> 4;        // H = 16

  const float* Qp = Q + ((size_t)bh * Sc + (size_t)qtile * QBLK) * Dc;
  const float* Kp = K + (size_t)bh * Sc * Dc;
  const float* Vp = V + (size_t)bh * Sc * Dc;
  const int*   Mp = M + (size_t)b * Sc * Sc + (size_t)qtile * QBLK * Sc;
  float*       Op = O + ((size_t)bh * Sc + (size_t)qtile * QBLK) * Dc;

  __shared__ _Float16 Klds [KVBLK][LDSW];  // K rows (key-major), fp16
  __shared__ _Float16 Vtlds[Dc]   [LDSW];  // V transposed: [d][key]
  __shared__ _Float16 Plds [QBLK] [LDSW];  // P tile, per-wave private rows

  const int tid = threadIdx.x;
  const int w   = tid >> 6;   // wave 0..3 -> q rows [w*16, w*16+16)
  const int l   = tid & 63;
  const int lg  = l >> 4;     // 0..3
  const int lc  = l & 15;     // 0..15

  // ---- Q fragments in registers, scale (1/8)*log2(e) folded into convert ----
  // A-frag layout: row = lane&15, k = 8*(lane>>4) + e  (contiguous 8)
  f16x8 qf[2];
  {
    const float qs = 0.125f * 1.4426950408889634f;
    const float* qrow = Qp + (size_t)(w * 16 + lc) * Dc + 8 * lg;
    #pragma unroll
    for (int ks = 0; ks < 2; ++ks) {
      f16x8 t;
      #pragma unroll
      for (int e = 0; e < 8; ++e) t[e] = (_Float16)(qrow[ks * 32 + e] * qs);
      qf[ks] = t;
    }
  }

  f32x4 o_acc[4];
  #pragma unroll
  for (int nt = 0; nt < 4; ++nt) o_acc[nt] = (f32x4){0.f, 0.f, 0.f, 0.f};
  float m_r[4], l_r[4];
  #pragma unroll
  for (int r = 0; r < 4; ++r) { m_r[r] = -3.0e38f; l_r[r] = 0.f; }

  const float NEGL = -1.4426950e9f;  // -1e9 * log2(e): masked score in exp2 domain

  for (int kv = 0; kv < NKV; ++kv) {
    const float* Kt = Kp + (size_t)kv * KVBLK * Dc;
    const float* Vt = Vp + (size_t)kv * KVBLK * Dc;

    __syncthreads();  // previous tile's MFMA reads done before overwrite

    // ---- stage K tile: row-major fp16, coalesced float4 loads ----
    {
      const int r = tid >> 2, c0 = (tid & 3) * 16;
      const float* src = Kt + (size_t)r * Dc + c0;
      f16x8 h0, h1;
      #pragma unroll
      for (int e = 0; e < 8; ++e) h0[e] = (_Float16)src[e];
      #pragma unroll
      for (int e = 0; e < 8; ++e) h1[e] = (_Float16)src[8 + e];
      *(f16x8*)&Klds[r][c0]     = h0;
      *(f16x8*)&Klds[r][c0 + 8] = h1;
    }
    // ---- stage V transposed: 4x4 block per thread, b64 LDS writes ----
    {
      const int r0 = (tid >> 4) * 4, c0 = (tid & 15) * 4;
      float a_[4][4];
      #pragma unroll
      for (int i = 0; i < 4; ++i) {
        const float4 v4 = *(const float4*)(Vt + (size_t)(r0 + i) * Dc + c0);
        a_[i][0] = v4.x; a_[i][1] = v4.y; a_[i][2] = v4.z; a_[i][3] = v4.w;
      }
      #pragma unroll
      for (int j = 0; j < 4; ++j) {
        f16x4 t = {(_Float16)a_[0][j], (_Float16)a_[1][j],
                   (_Float16)a_[2][j], (_Float16)a_[3][j]};
        *(f16x4*)&Vtlds[c0 + j][r0] = t;
      }
    }
    __syncthreads();

    // ---- S = (Q*scale) K^T via MFMA; acc reg r -> q row 4*lg+r, col nt*16+lc ----
    f32x4 s_acc[4];
    #pragma unroll
    for (int nt = 0; nt < 4; ++nt) {
      f32x4 acc = (f32x4){0.f, 0.f, 0.f, 0.f};
      #pragma unroll
      for (int ks = 0; ks < 2; ++ks) {
        f16x8 kf = *(const f16x8*)&Klds[nt * 16 + lc][ks * 32 + 8 * lg];
        acc = __builtin_amdgcn_mfma_f32_16x16x32_f16(qf[ks], kf, acc, 0, 0, 0);
      }
      s_acc[nt] = acc;
    }

    // ---- mask + online softmax (wave-parallel row reduce over 16 lanes) ----
    const int* mbase = Mp + (size_t)kv * KVBLK + lc;
    #pragma unroll
    for (int r = 0; r < 4; ++r) {
      const int qrow = w * 16 + 4 * lg + r;
      const int* mr = mbase + (size_t)qrow * Sc;
      float s0 = (mr[0]  != 0) ? s_acc[0][r] : NEGL;
      float s1 = (mr[16] != 0) ? s_acc[1][r] : NEGL;
      float s2 = (mr[32] != 0) ? s_acc[2][r] : NEGL;
      float s3 = (mr[48] != 0) ? s_acc[3][r] : NEGL;
      float mx = fmaxf(fmaxf(s0, s1), fmaxf(s2, s3));
      #pragma unroll
      for (int off = 1; off < 16; off <<= 1)
        mx = fmaxf(mx, __shfl_xor(mx, off, 64));
      const float mn   = fmaxf(m_r[r], mx);
      const float corr = fast_exp2(m_r[r] - mn);
      m_r[r] = mn;
      float p0 = fast_exp2(s0 - mn);
      float p1 = fast_exp2(s1 - mn);
      float p2 = fast_exp2(s2 - mn);
      float p3 = fast_exp2(s3 - mn);
      float rs = (p0 + p1) + (p2 + p3);
      #pragma unroll
      for (int off = 1; off < 16; off <<= 1)
        rs += __shfl_xor(rs, off, 64);
      l_r[r] = l_r[r] * corr + rs;
      #pragma unroll
      for (int nt = 0; nt < 4; ++nt) o_acc[nt][r] *= corr;
      // P tile to LDS (D-layout -> A-layout transpose via LDS), fp16
      Plds[qrow][lc]      = (_Float16)p0;
      Plds[qrow][16 + lc] = (_Float16)p1;
      Plds[qrow][32 + lc] = (_Float16)p2;
      Plds[qrow][48 + lc] = (_Float16)p3;
    }

    // ---- O += P V  (A = P from LDS, B = V^T from LDS) ----
    #pragma unroll
    for (int nt = 0; nt < 4; ++nt) {
      #pragma unroll
      for (int ks = 0; ks < 2; ++ks) {
        f16x8 pf = *(const f16x8*)&Plds [w * 16 + lc][ks * 32 + 8 * lg];
        f16x8 vf = *(const f16x8*)&Vtlds[nt * 16 + lc][ks * 32 + 8 * lg];
        o_acc[nt] = __builtin_amdgcn_mfma_f32_16x16x32_f16(pf, vf, o_acc[nt], 0, 0, 0);
      }
    }
  }

  // ---- epilogue: O /= l, fp32 coalesced stores ----
  #pragma unroll
  for (int r = 0; r < 4; ++r) {
    const float inv = 1.0f / l_r[r];
    float* orow = Op + (size_t)(w * 16 + 4 * lg + r) * Dc;
    #pragma unroll
    for (int nt = 0; nt < 4; ++nt)
      orow[nt * 16 + lc] = o_acc[nt][r] * inv;
  }
}

extern "C" void kernel_launch(void* const* d_in, const int* in_sizes, int n_in,
                              void* d_out, int out_size, void* d_ws, size_t ws_size,
                              hipStream_t stream) {
  (void)in_sizes; (void)n_in; (void)d_ws; (void)ws_size; (void)out_size;
  const float* Q = (const float*)d_in[0];
  const float* K = (const float*)d_in[1];
  const float* V = (const float*)d_in[2];
  const int*   M = (const int*)d_in[3];
  float*       O = (float*)d_out;
  dim3 grid(Bc * Hc * NQ);  // 2048 blocks
  dim3 blk(256);
  hipLaunchKernelGGL(attn_fwd, grid, blk, 0, stream, Q, K, V, M, O);
}